// Round 6
// baseline (412.462 us; speedup 1.0000x reference)
//
#include <hip/hip_runtime.h>
#include <hip/hip_bf16.h>
#include <math.h>

// Problem constants (HC2MMoE)
#define B_    16384
#define IN_   1024
#define E_    6
#define D_    20
#define EH1_  256
#define EH2_  128
#define EO_   10
#define GH_   64
#define TH_   64

typedef short  s16x8 __attribute__((ext_vector_type(8)));   // 8 bf16 = 4 VGPRs
typedef float  f32x4 __attribute__((ext_vector_type(4)));

__device__ inline ushort f2bf(float f) {   // RNE fp32 -> bf16 bits
    union { float f; uint32_t u; } v; v.f = f;
    return (ushort)((v.u + 0x7fffu + ((v.u >> 16) & 1u)) >> 16);
}
__device__ inline float bf2f(ushort u) {
    union { uint32_t u; float f; } v; v.u = ((uint32_t)u) << 16;
    return v.f;
}

#define GLOBAL_LDS16(g, l)                                                     \
    __builtin_amdgcn_global_load_lds(                                          \
        (const __attribute__((address_space(1))) void*)(g),                    \
        (__attribute__((address_space(3))) void*)(l), 16, 0, 0)

// ---------------------------------------------------------------------------
// Domain bucketing
// ---------------------------------------------------------------------------
__global__ void k_hist(const int* __restrict__ dom, int* __restrict__ hist) {
    int g = blockIdx.x * blockDim.x + threadIdx.x;
    if (g < B_) atomicAdd(&hist[dom[g]], 1);
}
__global__ void k_prefix(const int* __restrict__ hist, int* __restrict__ baseA,
                         int* __restrict__ cursor) {
    if (threadIdx.x == 0) {
        int s = 0;
        for (int i = 0; i < D_; ++i) { baseA[i] = s; cursor[i] = s; s += hist[i]; }
    }
}
__global__ void k_scatter(const int* __restrict__ dom, int* __restrict__ cursor,
                          int* __restrict__ perm) {
    int g = blockIdx.x * blockDim.x + threadIdx.x;
    if (g < B_) {
        int pos = atomicAdd(&cursor[dom[g]], 1);
        perm[pos] = g;
    }
}

// ---------------------------------------------------------------------------
// fp32 -> bf16 convert (x), 4 elems/thread; block 0 also zeroes hist
// ---------------------------------------------------------------------------
__global__ __launch_bounds__(256) void k_cvt(const float* __restrict__ src,
                                             ushort* __restrict__ dst,
                                             int* __restrict__ hist) {
    if (blockIdx.x == 0 && threadIdx.x < D_) hist[threadIdx.x] = 0;
    int i = blockIdx.x * 256 + threadIdx.x;
    float4 v = ((const float4*)src)[i];
    ushort4 o;
    o.x = f2bf(v.x); o.y = f2bf(v.y); o.z = f2bf(v.z); o.w = f2bf(v.w);
    ((ushort4*)dst)[i] = o;
}

// ---------------------------------------------------------------------------
// Weight transpose + convert: W [Z][K][N] fp32 -> Wt [Z][N][K] bf16
// ---------------------------------------------------------------------------
__global__ __launch_bounds__(256) void k_wt(const float* __restrict__ W,
                                            ushort* __restrict__ Wt,
                                            int K, int N) {
    __shared__ float tile[32][33];
    const int e = blockIdx.z;
    const int n0 = blockIdx.x * 32, k0 = blockIdx.y * 32;
    const float* We = W + (size_t)e * K * N;
    ushort* Wte = Wt + (size_t)e * K * N;
    const int lx = threadIdx.x & 31, ly = threadIdx.x >> 5;   // ly 0..7
    #pragma unroll
    for (int r = 0; r < 4; ++r)
        tile[ly + r * 8][lx] = We[(size_t)(k0 + ly + r * 8) * N + n0 + lx];
    __syncthreads();
    #pragma unroll
    for (int r = 0; r < 4; ++r)
        Wte[(size_t)(n0 + ly + r * 8) * K + k0 + lx] = f2bf(tile[lx][ly + r * 8]);
}

// ---------------------------------------------------------------------------
// XOR bank-swizzle (verified R5: conflicts -> 0): within each 32-elem k-window
// staged via global_load_lds, physical 16B granule (row, c) holds global chunk
// c ^ ((row>>1)&3). Store side: global k-off = ((lane-chunk) ^ s)*8; read side:
// physical chunk = (quad ^ ((row>>1)&3)).
// ---------------------------------------------------------------------------

#define GBK 32
#define H2P 136   // padded row stride for h1L/h2L/E3t (normal ds_write tiles)

// ---------------------------------------------------------------------------
// One-pass expert kernel: per (128-row tile, expert e) block computes
//   h1 = relu(x.W1^T+b1)  [128x256, two 128-col halves, MFMA, h1 kept in LDS]
//   h2 = relu(h1.W2^T+b2) [128x128, accumulated in VGPRs across halves]
//   eo = h2.Ew3+b3        [128x10, MFMA vs zero-padded 16-col B]
// No h1/h2 global traffic. LDS: 32KB staging union + 34.8KB tile = 66KB
// -> 2 blocks/CU.
// ---------------------------------------------------------------------------
__global__ __launch_bounds__(256) void k_expert(
        const ushort* __restrict__ xb, const ushort* __restrict__ W1t,
        const float* __restrict__ Eb1, const ushort* __restrict__ W2t,
        const float* __restrict__ Eb2, const float* __restrict__ Ew3,
        const float* __restrict__ Eb3, float* __restrict__ eo) {
    __shared__ __attribute__((aligned(16))) ushort smem[16384 + 128 * H2P];
    ushort* reg0 = smem;            // 32KB union: As|Bs (L1), W2s (L2), E3t (L3)
    ushort* AsL  = smem;            // [128][32] swizzled
    ushort* BsL  = smem + 4096;     // [128][32] swizzled
    ushort* h1L  = smem + 16384;    // [128][H2P] padded (plain ds_write)

    const int e  = blockIdx.y;
    const int m0 = blockIdx.x * 128;
    const ushort* W1e = W1t + (size_t)e * EH1_ * IN_;    // [256][1024]
    const ushort* W2e = W2t + (size_t)e * EH2_ * EH1_;   // [128][256]

    const int t = threadIdx.x;
    const int wave = t >> 6;
    const int lane = t & 63;

    const int q0 = wave * 2, q1 = q0 + 1;
    const int sr0 = q0 * 16 + (lane >> 2);
    const int sr1 = sr0 + 16;                       // (sr1>>1)&3 == (sr0>>1)&3
    const int sw  = ((lane & 3) ^ ((sr0 >> 1) & 3)) * 8;

    const int quad = lane >> 4;
    const int l16  = lane & 15;
    const int qsw  = (quad ^ ((l16 >> 1) & 3)) * 8;
    const int rw = (wave & 1) * 64;
    const int cw = (wave >> 1) * 64;

    f32x4 acc2[4][4] = {};   // h2 accumulator, wave's 64x64 quadrant

    for (int half = 0; half < 2; ++half) {
        const int n1 = half * 128;
        f32x4 acc1[4][4] = {};

        // ---- L1: 128 x 128(half) x 1024, m97 staging ----
        for (int k0 = 0; k0 < IN_; k0 += GBK) {
            GLOBAL_LDS16(xb  + (size_t)(m0 + sr0) * IN_ + k0 + sw, AsL + q0 * 512);
            GLOBAL_LDS16(xb  + (size_t)(m0 + sr1) * IN_ + k0 + sw, AsL + q1 * 512);
            GLOBAL_LDS16(W1e + (size_t)(n1 + sr0) * IN_ + k0 + sw, BsL + q0 * 512);
            GLOBAL_LDS16(W1e + (size_t)(n1 + sr1) * IN_ + k0 + sw, BsL + q1 * 512);
            __syncthreads();

            s16x8 af[4], bf[4];
            #pragma unroll
            for (int i = 0; i < 4; ++i)
                af[i] = *(const s16x8*)&AsL[(rw + 16 * i + l16) * GBK + qsw];
            #pragma unroll
            for (int j = 0; j < 4; ++j)
                bf[j] = *(const s16x8*)&BsL[(cw + 16 * j + l16) * GBK + qsw];
            #pragma unroll
            for (int i = 0; i < 4; ++i)
                #pragma unroll
                for (int j = 0; j < 4; ++j)
                    acc1[i][j] = __builtin_amdgcn_mfma_f32_16x16x32_bf16(
                        af[i], bf[j], acc1[i][j], 0, 0, 0);
            __syncthreads();
        }

        // ---- h1 half -> LDS (bias+relu, bf16), C-layout scatter ----
        {
            float bi1[4];
            #pragma unroll
            for (int j = 0; j < 4; ++j)
                bi1[j] = Eb1[e * EH1_ + n1 + cw + 16 * j + l16];
            #pragma unroll
            for (int i = 0; i < 4; ++i)
                #pragma unroll
                for (int r = 0; r < 4; ++r) {
                    int row = rw + 16 * i + quad * 4 + r;
                    #pragma unroll
                    for (int j = 0; j < 4; ++j)
                        h1L[row * H2P + cw + 16 * j + l16] =
                            f2bf(fmaxf(acc1[i][j][r] + bi1[j], 0.f));
                }
        }

        // ---- stage W2 k-slice, window-major [kc][128 rows][32], swizzled ----
        // wave w stages window kc=w; 8 chunks of 16 rows (same pattern as main
        // loop Bs -> identical conflict-free bank behavior).
        #pragma unroll
        for (int it = 0; it < 8; ++it) {
            int row = it * 16 + (lane >> 2);
            int q = lane & 3;
            GLOBAL_LDS16(W2e + (size_t)row * EH1_ + n1 + wave * 32 +
                             ((q ^ ((row >> 1) & 3)) * 8),
                         reg0 + wave * 4096 + it * 512);
        }
        __syncthreads();   // h1L + W2s visible

        // ---- L2 partial: acc2 += h1half . W2slice ----
        #pragma unroll
        for (int kc = 0; kc < 4; ++kc) {
            s16x8 af[4], bf[4];
            #pragma unroll
            for (int i = 0; i < 4; ++i)
                af[i] = *(const s16x8*)&h1L[(rw + 16 * i + l16) * H2P +
                                            kc * 32 + quad * 8];
            #pragma unroll
            for (int j = 0; j < 4; ++j) {
                int n2 = cw + 16 * j + l16;
                bf[j] = *(const s16x8*)&reg0[kc * 4096 + n2 * 32 +
                                             ((quad ^ ((n2 >> 1) & 3)) * 8)];
            }
            #pragma unroll
            for (int i = 0; i < 4; ++i)
                #pragma unroll
                for (int j = 0; j < 4; ++j)
                    acc2[i][j] = __builtin_amdgcn_mfma_f32_16x16x32_bf16(
                        af[i], bf[j], acc2[i][j], 0, 0, 0);
        }
        __syncthreads();   // before next half (or phase B) reuses LDS
    }

    // ---- Phase B: h2 -> LDS, Ew3 -> LDS, eo = h2.Ew3 + b3 ----
    ushort* h2L = h1L;              // reuse tile region
    ushort* E3t = reg0;             // [16][H2P], cols >= EO_ zero
    {
        float bi2[4];
        #pragma unroll
        for (int j = 0; j < 4; ++j) bi2[j] = Eb2[e * EH2_ + cw + 16 * j + l16];
        #pragma unroll
        for (int i = 0; i < 4; ++i)
            #pragma unroll
            for (int r = 0; r < 4; ++r) {
                int row = rw + 16 * i + quad * 4 + r;
                #pragma unroll
                for (int j = 0; j < 4; ++j)
                    h2L[row * H2P + cw + 16 * j + l16] =
                        f2bf(fmaxf(acc2[i][j][r] + bi2[j], 0.f));
            }
    }
    for (int i = t; i < 16 * 128; i += 256) {
        int col = i >> 7, k = i & 127;
        float v = (col < EO_) ? Ew3[(size_t)e * EH2_ * EO_ + k * EO_ + col] : 0.f;
        E3t[col * H2P + k] = f2bf(v);
    }
    __syncthreads();

    #pragma unroll
    for (int gi = 0; gi < 2; ++gi) {
        int g = wave * 2 + gi;
        f32x4 acc3 = {};
        #pragma unroll
        for (int kc = 0; kc < 4; ++kc) {
            s16x8 a = *(const s16x8*)&h2L[(g * 16 + l16) * H2P + kc * 32 + quad * 8];
            s16x8 b = *(const s16x8*)&E3t[l16 * H2P + kc * 32 + quad * 8];
            acc3 = __builtin_amdgcn_mfma_f32_16x16x32_bf16(a, b, acc3, 0, 0, 0);
        }
        if (l16 < EO_) {
            float b3 = Eb3[e * EO_ + l16];
            #pragma unroll
            for (int r = 0; r < 4; ++r) {
                int row = m0 + g * 16 + quad * 4 + r;
                eo[(size_t)row * (E_ * EO_) + e * EO_ + l16] = acc3[r] + b3;
            }
        }
    }
}

// ---------------------------------------------------------------------------
// Gate (MFMA, fused): per (domain, 64-row tile) block, with bank swizzle.
// ---------------------------------------------------------------------------
__global__ __launch_bounds__(256) void k_gate2(
        const ushort* __restrict__ xb, const ushort* __restrict__ Gw1t,
        const float* __restrict__ Gb1, const float* __restrict__ Gw2,
        const float* __restrict__ Gb2, const int* __restrict__ perm,
        const int* __restrict__ baseA, const int* __restrict__ cntA,
        float* __restrict__ gate) {
    const int d = blockIdx.y;
    const int cnt = cntA[d];
    const int start = blockIdx.x * 64;
    if (start >= cnt) return;
    const int base = baseA[d];

    __shared__ __attribute__((aligned(16))) ushort As[64 * 32];
    __shared__ __attribute__((aligned(16))) ushort Bs[64 * 32];
    __shared__ int    ridx[64];
    __shared__ float  gh[64][GH_ + 1];
    __shared__ float  w2s[GH_ * E_];
    __shared__ float  b2s[E_];
    __shared__ float  lg[64][E_];

    const int t = threadIdx.x;
    const int wave = t >> 6;
    const int lane = t & 63;
    const int quad = lane >> 4;
    const int l16  = lane & 15;
    const int qsw  = (quad ^ ((l16 >> 1) & 3)) * 8;

    if (t < 64) {
        int p = start + t;
        ridx[t] = (p < cnt) ? perm[base + p] : perm[base];  // clamp OOB
    }
    for (int i = t; i < GH_ * E_; i += 256) w2s[i] = Gw2[(size_t)d * GH_ * E_ + i];
    if (t < E_) b2s[t] = Gb2[d * E_ + t];
    __syncthreads();

    const int srow = t >> 2;
    const int sw   = ((t & 3) ^ ((srow >> 1) & 3)) * 8;
    const int myRow = ridx[srow];
    const ushort* aRow = xb + (size_t)myRow * IN_ + sw;
    const ushort* bRow = Gw1t + (size_t)d * GH_ * IN_ + (size_t)srow * IN_ + sw;

    f32x4 acc[4] = {};
    for (int k0 = 0; k0 < IN_; k0 += 32) {
        GLOBAL_LDS16(aRow + k0, As + wave * 512);
        GLOBAL_LDS16(bRow + k0, Bs + wave * 512);
        __syncthreads();

        s16x8 bf = *(const s16x8*)&Bs[(wave * 16 + l16) * 32 + qsw];
        #pragma unroll
        for (int i = 0; i < 4; ++i) {
            s16x8 af = *(const s16x8*)&As[(16 * i + l16) * 32 + qsw];
            acc[i] = __builtin_amdgcn_mfma_f32_16x16x32_bf16(af, bf, acc[i], 0, 0, 0);
        }
        __syncthreads();
    }

    const int hcol = wave * 16 + l16;
    float hb = Gb1[d * GH_ + hcol];
    #pragma unroll
    for (int i = 0; i < 4; ++i)
        #pragma unroll
        for (int r = 0; r < 4; ++r)
            gh[16 * i + quad * 4 + r][hcol] = fmaxf(acc[i][r] + hb, 0.f);
    __syncthreads();

    // layer 2: 64 rows x 6 experts = 384 pairs, strided over 256 threads
    for (int p = t; p < 64 * E_; p += 256) {
        int row = p / E_, e = p - row * E_;
        float s = b2s[e];
        #pragma unroll 8
        for (int h = 0; h < GH_; ++h) s += gh[row][h] * w2s[h * E_ + e];
        lg[row][e] = s;
    }
    __syncthreads();

    if (t < 64 && start + t < cnt) {
        int b = ridx[t];
        float mx = lg[t][0];
        #pragma unroll
        for (int e = 1; e < E_; ++e) mx = fmaxf(mx, lg[t][e]);
        float ex[E_], sum = 0.f;
        #pragma unroll
        for (int e = 0; e < E_; ++e) { ex[e] = expf(lg[t][e] - mx); sum += ex[e]; }
        float inv = 1.f / sum;
        #pragma unroll
        for (int e = 0; e < E_; ++e) gate[(size_t)b * E_ + e] = ex[e] * inv;
    }
}

// ---------------------------------------------------------------------------
// Final: MMoE combine + avg + tower, one wave per sample
// ---------------------------------------------------------------------------
__global__ __launch_bounds__(256) void k_final(
        const float* __restrict__ eo, const float* __restrict__ gate,
        const int* __restrict__ dom,
        const float* __restrict__ Tw1, const float* __restrict__ Tb1,
        const float* __restrict__ Tw2, const float* __restrict__ Tb2,
        float* __restrict__ out) {
    const int wave = threadIdx.x >> 6;
    const int lane = threadIdx.x & 63;
    const int b = blockIdx.x * 4 + wave;
    const int d = dom[b];

    const float* eob = eo + (size_t)b * (E_ * EO_);
    float g[E_];
    #pragma unroll
    for (int e = 0; e < E_; ++e) g[e] = gate[(size_t)b * E_ + e];

    float mmoe[EO_], avg[EO_];
    #pragma unroll
    for (int o = 0; o < EO_; ++o) {
        float m = 0.f, a = 0.f;
        #pragma unroll
        for (int e = 0; e < E_; ++e) {
            float v = eob[e * EO_ + o];
            m += g[e] * v;
            a += v;
        }
        mmoe[o] = m;
        avg[o] = a * (1.0f / E_);
    }

    float acc = Tb1[d * TH_ + lane];
    #pragma unroll
    for (int o = 0; o < EO_; ++o)
        acc += mmoe[o] * Tw1[(size_t)d * EO_ * TH_ + o * TH_ + lane];
    acc = fmaxf(acc, 0.f);

    float s = acc * Tw2[d * TH_ + lane];
    #pragma unroll
    for (int off = 32; off >= 1; off >>= 1) s += __shfl_xor(s, off, 64);

    if (lane == 0)
        out[b] = 1.f / (1.f + expf(-(s + Tb2[d])));
    if (lane < EO_) {
        out[B_ + (size_t)b * EO_ + lane] = avg[lane];
        out[B_ + (size_t)B_ * EO_ + (size_t)b * EO_ + lane] = mmoe[lane];
    }
}

// ---------------------------------------------------------------------------
extern "C" void kernel_launch(void* const* d_in, const int* in_sizes, int n_in,
                              void* d_out, int out_size, void* d_ws, size_t ws_size,
                              hipStream_t stream) {
    const float* x   = (const float*)d_in[0];
    const int*   dom = (const int*)d_in[1];
    const float* Ew1 = (const float*)d_in[2];
    const float* Eb1 = (const float*)d_in[3];
    const float* Ew2 = (const float*)d_in[4];
    const float* Eb2 = (const float*)d_in[5];
    const float* Ew3 = (const float*)d_in[6];
    const float* Eb3 = (const float*)d_in[7];
    const float* Gw1 = (const float*)d_in[8];
    const float* Gb1 = (const float*)d_in[9];
    const float* Gw2 = (const float*)d_in[10];
    const float* Gb2 = (const float*)d_in[11];
    const float* Tw1 = (const float*)d_in[12];
    const float* Tb1 = (const float*)d_in[13];
    const float* Tw2 = (const float*)d_in[14];
    const float* Tb2 = (const float*)d_in[15];
    float* out = (float*)d_out;

    char* ws = (char*)d_ws;
    size_t off = 0;
    auto take = [&](size_t bytes) -> char* {
        char* p = ws + off;
        off = (off + bytes + 255) & ~(size_t)255;
        return p;
    };
    int*    hist    = (int*)take(D_ * 4);
    int*    baseA   = (int*)take(D_ * 4);
    int*    cursor  = (int*)take(D_ * 4);
    int*    perm    = (int*)take(B_ * 4);
    float*  gateBuf = (float*)take((size_t)B_ * E_ * 4);
    float*  eoBuf   = (float*)take((size_t)B_ * E_ * EO_ * 4);
    ushort* xb      = (ushort*)take((size_t)B_ * IN_ * 2);
    ushort* W1t     = (ushort*)take((size_t)E_ * IN_ * EH1_ * 2);
    ushort* W2t     = (ushort*)take((size_t)E_ * EH1_ * EH2_ * 2);
    ushort* G1t     = (ushort*)take((size_t)D_ * IN_ * GH_ * 2);
    (void)ws_size;

    // conversions (+hist zero inside k_cvt)
    k_cvt<<<dim3(B_ * IN_ / 4 / 256), dim3(256), 0, stream>>>(x, xb, hist);
    k_wt<<<dim3(EH1_ / 32, IN_ / 32, E_), dim3(256), 0, stream>>>(Ew1, W1t, IN_, EH1_);
    k_wt<<<dim3(EH2_ / 32, EH1_ / 32, E_), dim3(256), 0, stream>>>(Ew2, W2t, EH1_, EH2_);
    k_wt<<<dim3(GH_ / 32, IN_ / 32, D_), dim3(256), 0, stream>>>(Gw1, G1t, IN_, GH_);

    // domain bucketing
    k_hist<<<dim3(B_ / 256), dim3(256), 0, stream>>>(dom, hist);
    k_prefix<<<dim3(1), dim3(32), 0, stream>>>(hist, baseA, cursor);
    k_scatter<<<dim3(B_ / 256), dim3(256), 0, stream>>>(dom, cursor, perm);

    // gates (selected domain only, MFMA + fused softmax)
    k_gate2<<<dim3((B_ + 63) / 64, D_), dim3(256), 0, stream>>>(
        xb, G1t, Gb1, Gw2, Gb2, perm, baseA, hist, gateBuf);

    // experts: one-pass L1+L2+L3 (no h1/h2 global traffic)
    k_expert<<<dim3(B_ / 128, E_), dim3(256), 0, stream>>>(
        xb, W1t, Eb1, W2t, Eb2, Ew3, Eb3, eoBuf);

    // combine + towers + outputs
    k_final<<<dim3(B_ / 4), dim3(256), 0, stream>>>(
        eoBuf, gateBuf, dom, Tw1, Tb1, Tw2, Tb2, out);
}

// Round 7
// 329.911 us; speedup vs baseline: 1.2502x; 1.2502x over previous
//
#include <hip/hip_runtime.h>
#include <hip/hip_bf16.h>
#include <math.h>

// Problem constants (HC2MMoE)
#define B_    16384
#define IN_   1024
#define E_    6
#define D_    20
#define EH1_  256
#define EH2_  128
#define EO_   10
#define GH_   64
#define TH_   64

typedef short  s16x8 __attribute__((ext_vector_type(8)));   // 8 bf16 = 4 VGPRs
typedef float  f32x4 __attribute__((ext_vector_type(4)));

__device__ inline ushort f2bf(float f) {   // RNE fp32 -> bf16 bits
    union { float f; uint32_t u; } v; v.f = f;
    return (ushort)((v.u + 0x7fffu + ((v.u >> 16) & 1u)) >> 16);
}
__device__ inline float bf2f(ushort u) {
    union { uint32_t u; float f; } v; v.u = ((uint32_t)u) << 16;
    return v.f;
}

#define GLOBAL_LDS16(g, l)                                                     \
    __builtin_amdgcn_global_load_lds(                                          \
        (const __attribute__((address_space(1))) void*)(g),                    \
        (__attribute__((address_space(3))) void*)(l), 16, 0, 0)

// ---------------------------------------------------------------------------
// Prep: fused x-convert + 3 weight transposes. Flat grid, uniform per-block
// branch.  cvt blocks [0, 16384); wt tiles follow.
// ---------------------------------------------------------------------------
#define CVT_BLKS  (B_ * IN_ / 4 / 256)                       // 16384
#define WT1_TILES ((EH1_ / 32) * (IN_ / 32) * E_)            // 1536
#define WT2_TILES ((EH2_ / 32) * (EH1_ / 32) * E_)           // 192
#define WTG_TILES ((GH_ / 32) * (IN_ / 32) * D_)             // 1280
#define PREP_BLKS (CVT_BLKS + WT1_TILES + WT2_TILES + WTG_TILES)

__global__ __launch_bounds__(256) void k_prep(
        const float* __restrict__ x, ushort* __restrict__ xb,
        const float* __restrict__ Ew1, ushort* __restrict__ W1t,
        const float* __restrict__ Ew2, ushort* __restrict__ W2t,
        const float* __restrict__ Gw1, ushort* __restrict__ G1t) {
    __shared__ float tile[32][33];
    int bid = blockIdx.x;
    const int t = threadIdx.x;

    if (bid < CVT_BLKS) {
        int i = bid * 256 + t;
        float4 v = ((const float4*)x)[i];
        ushort4 o;
        o.x = f2bf(v.x); o.y = f2bf(v.y); o.z = f2bf(v.z); o.w = f2bf(v.w);
        ((ushort4*)xb)[i] = o;
        return;
    }
    bid -= CVT_BLKS;

    const float* W; ushort* Wt; int K, N, z, ky, nx;
    if (bid < WT1_TILES) {
        W = Ew1; Wt = W1t; K = IN_; N = EH1_;
        z = bid / (8 * 32); int r = bid % (8 * 32); ky = r / 8; nx = r % 8;
    } else if (bid < WT1_TILES + WT2_TILES) {
        bid -= WT1_TILES;
        W = Ew2; Wt = W2t; K = EH1_; N = EH2_;
        z = bid / (4 * 8); int r = bid % (4 * 8); ky = r / 4; nx = r % 4;
    } else {
        bid -= WT1_TILES + WT2_TILES;
        W = Gw1; Wt = G1t; K = IN_; N = GH_;
        z = bid / (2 * 32); int r = bid % (2 * 32); ky = r / 2; nx = r % 2;
    }
    const int n0 = nx * 32, k0 = ky * 32;
    const float* We = W + (size_t)z * K * N;
    ushort* Wte = Wt + (size_t)z * K * N;
    const int lx = t & 31, ly = t >> 5;
    #pragma unroll
    for (int r = 0; r < 4; ++r)
        tile[ly + r * 8][lx] = We[(size_t)(k0 + ly + r * 8) * N + n0 + lx];
    __syncthreads();
    #pragma unroll
    for (int r = 0; r < 4; ++r)
        Wte[(size_t)(n0 + ly + r * 8) * K + k0 + lx] = f2bf(tile[lx][ly + r * 8]);
}

// ---------------------------------------------------------------------------
// Fused histogram + prefix (single block, LDS atomics)
// ---------------------------------------------------------------------------
__global__ __launch_bounds__(256) void k_prefix2(
        const int* __restrict__ dom, int* __restrict__ hist,
        int* __restrict__ baseA, int* __restrict__ cursor) {
    __shared__ int h[D_];
    const int t = threadIdx.x;
    if (t < D_) h[t] = 0;
    __syncthreads();
    for (int i = t; i < B_; i += 256) atomicAdd(&h[dom[i]], 1);
    __syncthreads();
    if (t == 0) {
        int s = 0;
        for (int i = 0; i < D_; ++i) {
            baseA[i] = s; cursor[i] = s; hist[i] = h[i]; s += h[i];
        }
    }
}

__global__ void k_scatter(const int* __restrict__ dom, int* __restrict__ cursor,
                          int* __restrict__ perm) {
    int g = blockIdx.x * blockDim.x + threadIdx.x;
    if (g < B_) {
        int pos = atomicAdd(&cursor[dom[g]], 1);
        perm[pos] = g;
    }
}

// ---------------------------------------------------------------------------
// XOR bank-swizzle (verified R5: conflicts -> 0): within each 32-elem k-window
// staged via global_load_lds, physical 16B granule (row, c) holds global chunk
// c ^ ((row>>1)&3).
// ---------------------------------------------------------------------------
#define GBK 32
#define CSP 136   // padded row stride (elems) for epilogue repack / l2eo tiles
#define H2P 136

// bf16 MFMA GEMM: C = relu(A . W + bias), bf16 out. 128x128 tile, BK=32.
// Epilogue: two-phase LDS repack -> fully coalesced 16B/lane stores.
__global__ __launch_bounds__(256) void k_mfma_gemm(
        const ushort* __restrict__ A, size_t aStride,
        const ushort* __restrict__ Wt, const float* __restrict__ Bias,
        ushort* __restrict__ C, int M, int N, int K, int eBase) {
    __shared__ __attribute__((aligned(16))) ushort smem[64 * CSP]; // >= 8192
    ushort* As = smem;            // [128][32] swizzled (K-loop)
    ushort* Bs = smem + 4096;     // [128][32] swizzled (K-loop)

    const int z = blockIdx.z;
    const int eAbs = eBase + z;
    const ushort* Ae = A + (size_t)z * aStride;
    const ushort* We = Wt + (size_t)eAbs * (size_t)N * K;
    const float* BiasE = Bias + (size_t)eAbs * N;
    ushort* Ce = C + (size_t)z * (size_t)M * N;

    const int m0 = blockIdx.y * 128;
    const int n0 = blockIdx.x * 128;
    const int t = threadIdx.x;
    const int wave = t >> 6;
    const int lane = t & 63;

    const int q0 = wave * 2, q1 = q0 + 1;
    const int sr0 = q0 * 16 + (lane >> 2);
    const int sr1 = sr0 + 16;                       // (sr1>>1)&3 == (sr0>>1)&3
    const int sw  = ((lane & 3) ^ ((sr0 >> 1) & 3)) * 8;

    const int quad = lane >> 4;
    const int l16  = lane & 15;
    const int qsw  = (quad ^ ((l16 >> 1) & 3)) * 8;
    const int rw = (wave & 1) * 64;
    const int cw = (wave >> 1) * 64;

    f32x4 acc[4][4] = {};

    for (int k0 = 0; k0 < K; k0 += GBK) {
        GLOBAL_LDS16(Ae + (size_t)(m0 + sr0) * K + k0 + sw, As + q0 * 512);
        GLOBAL_LDS16(Ae + (size_t)(m0 + sr1) * K + k0 + sw, As + q1 * 512);
        GLOBAL_LDS16(We + (size_t)(n0 + sr0) * K + k0 + sw, Bs + q0 * 512);
        GLOBAL_LDS16(We + (size_t)(n0 + sr1) * K + k0 + sw, Bs + q1 * 512);
        __syncthreads();

        s16x8 af[4], bf[4];
        #pragma unroll
        for (int i = 0; i < 4; ++i)
            af[i] = *(const s16x8*)&As[(rw + 16 * i + l16) * GBK + qsw];
        #pragma unroll
        for (int j = 0; j < 4; ++j)
            bf[j] = *(const s16x8*)&Bs[(cw + 16 * j + l16) * GBK + qsw];
        #pragma unroll
        for (int i = 0; i < 4; ++i)
            #pragma unroll
            for (int j = 0; j < 4; ++j)
                acc[i][j] = __builtin_amdgcn_mfma_f32_16x16x32_bf16(
                    af[i], bf[j], acc[i][j], 0, 0, 0);
        __syncthreads();
    }

    // epilogue: bias+relu -> bf16, two-phase LDS repack, coalesced stores
    float bi[4];
    #pragma unroll
    for (int j = 0; j < 4; ++j) bi[j] = BiasE[n0 + cw + 16 * j + l16];

    for (int ph = 0; ph < 2; ++ph) {
        __syncthreads();
        if ((wave & 1) == ph) {
            #pragma unroll
            for (int i = 0; i < 4; ++i)
                #pragma unroll
                for (int r = 0; r < 4; ++r) {
                    int row = 16 * i + quad * 4 + r;   // 0..63 in this group
                    #pragma unroll
                    for (int j = 0; j < 4; ++j)
                        smem[row * CSP + cw + 16 * j + l16] =
                            f2bf(fmaxf(acc[i][j][r] + bi[j], 0.f));
                }
        }
        __syncthreads();
        #pragma unroll
        for (int it = 0; it < 4; ++it) {
            int row = it * 16 + (t >> 4);
            int ch  = t & 15;
            s16x8 v = *(const s16x8*)&smem[row * CSP + ch * 8];
            *(s16x8*)(Ce + (size_t)(m0 + ph * 64 + row) * N + n0 + ch * 8) = v;
        }
    }
}

// ---------------------------------------------------------------------------
// Fused expert L2+L3 (unchanged from R5): h2 = relu(h1 . W2^T + Eb2), then
// eo = h2 . Ew3 + Eb3 in-block.
// ---------------------------------------------------------------------------
__global__ __launch_bounds__(256) void k_l2eo(
        const ushort* __restrict__ h1, const ushort* __restrict__ W2t,
        const float* __restrict__ Eb2, const float* __restrict__ Ew3,
        const float* __restrict__ Eb3, float* __restrict__ eo, int eBase) {
    __shared__ __attribute__((aligned(16))) ushort smem[17408 + 16 * H2P];
    ushort* As = smem;            // 128*32 elems (main loop)
    ushort* Bs = smem + 4096;     // 128*32 elems (main loop)

    const int z = blockIdx.y;
    const int eAbs = eBase + z;
    const ushort* Ae = h1 + (size_t)z * B_ * EH1_;
    const ushort* We = W2t + (size_t)eAbs * EH2_ * EH1_;   // [N=128][K=256]

    const int m0 = blockIdx.x * 128;
    const int t = threadIdx.x;
    const int wave = t >> 6;
    const int lane = t & 63;

    const int q0 = wave * 2, q1 = q0 + 1;
    const int sr0 = q0 * 16 + (lane >> 2);
    const int sr1 = sr0 + 16;
    const int sw  = ((lane & 3) ^ ((sr0 >> 1) & 3)) * 8;

    const int quad = lane >> 4;
    const int l16  = lane & 15;
    const int qsw  = (quad ^ ((l16 >> 1) & 3)) * 8;
    const int rw = (wave & 1) * 64;
    const int cw = (wave >> 1) * 64;

    f32x4 acc[4][4] = {};

    for (int k0 = 0; k0 < EH1_; k0 += GBK) {
        GLOBAL_LDS16(Ae + (size_t)(m0 + sr0) * EH1_ + k0 + sw, As + q0 * 512);
        GLOBAL_LDS16(Ae + (size_t)(m0 + sr1) * EH1_ + k0 + sw, As + q1 * 512);
        GLOBAL_LDS16(We + (size_t)sr0 * EH1_ + k0 + sw, Bs + q0 * 512);
        GLOBAL_LDS16(We + (size_t)sr1 * EH1_ + k0 + sw, Bs + q1 * 512);
        __syncthreads();

        s16x8 af[4], bf[4];
        #pragma unroll
        for (int i = 0; i < 4; ++i)
            af[i] = *(const s16x8*)&As[(rw + 16 * i + l16) * GBK + qsw];
        #pragma unroll
        for (int j = 0; j < 4; ++j)
            bf[j] = *(const s16x8*)&Bs[(cw + 16 * j + l16) * GBK + qsw];
        #pragma unroll
        for (int i = 0; i < 4; ++i)
            #pragma unroll
            for (int j = 0; j < 4; ++j)
                acc[i][j] = __builtin_amdgcn_mfma_f32_16x16x32_bf16(
                    af[i], bf[j], acc[i][j], 0, 0, 0);
        __syncthreads();
    }

    // epilogue: h2 tile (bias+relu, bf16) -> LDS in A-readable layout
    ushort* h2L = smem;             // [128][H2P]
    ushort* E3t = smem + 128 * H2P; // [16][H2P]  (cols >= EO_ zero)

    float bi[4];
    #pragma unroll
    for (int j = 0; j < 4; ++j) bi[j] = Eb2[eAbs * EH2_ + cw + 16 * j + l16];

    #pragma unroll
    for (int i = 0; i < 4; ++i)
        #pragma unroll
        for (int r = 0; r < 4; ++r) {
            int row = rw + 16 * i + quad * 4 + r;
            #pragma unroll
            for (int j = 0; j < 4; ++j)
                h2L[row * H2P + cw + 16 * j + l16] =
                    f2bf(fmaxf(acc[i][j][r] + bi[j], 0.f));
        }

    for (int i = t; i < 16 * 128; i += 256) {
        int col = i >> 7, k = i & 127;
        float v = (col < EO_) ? Ew3[(size_t)eAbs * EH2_ * EO_ + k * EO_ + col] : 0.f;
        E3t[col * H2P + k] = f2bf(v);
    }
    __syncthreads();

    #pragma unroll
    for (int gi = 0; gi < 2; ++gi) {
        int g = wave * 2 + gi;
        f32x4 acc2 = {};
        #pragma unroll
        for (int kc = 0; kc < 4; ++kc) {
            s16x8 a = *(const s16x8*)&h2L[(g * 16 + l16) * H2P + kc * 32 + quad * 8];
            s16x8 b = *(const s16x8*)&E3t[l16 * H2P + kc * 32 + quad * 8];
            acc2 = __builtin_amdgcn_mfma_f32_16x16x32_bf16(a, b, acc2, 0, 0, 0);
        }
        if (l16 < EO_) {
            float b3 = Eb3[eAbs * EO_ + l16];
            #pragma unroll
            for (int r = 0; r < 4; ++r) {
                int row = m0 + g * 16 + quad * 4 + r;
                eo[(size_t)row * (E_ * EO_) + eAbs * EO_ + l16] = acc2[r] + b3;
            }
        }
    }
}

// ---------------------------------------------------------------------------
// Gate (MFMA, fused): per (domain, 64-row tile) block, with bank swizzle.
// ---------------------------------------------------------------------------
__global__ __launch_bounds__(256) void k_gate2(
        const ushort* __restrict__ xb, const ushort* __restrict__ Gw1t,
        const float* __restrict__ Gb1, const float* __restrict__ Gw2,
        const float* __restrict__ Gb2, const int* __restrict__ perm,
        const int* __restrict__ baseA, const int* __restrict__ cntA,
        float* __restrict__ gate) {
    const int d = blockIdx.y;
    const int cnt = cntA[d];
    const int start = blockIdx.x * 64;
    if (start >= cnt) return;
    const int base = baseA[d];

    __shared__ __attribute__((aligned(16))) ushort As[64 * 32];
    __shared__ __attribute__((aligned(16))) ushort Bs[64 * 32];
    __shared__ int    ridx[64];
    __shared__ float  gh[64][GH_ + 1];
    __shared__ float  w2s[GH_ * E_];
    __shared__ float  b2s[E_];
    __shared__ float  lg[64][E_];

    const int t = threadIdx.x;
    const int wave = t >> 6;
    const int lane = t & 63;
    const int quad = lane >> 4;
    const int l16  = lane & 15;
    const int qsw  = (quad ^ ((l16 >> 1) & 3)) * 8;

    if (t < 64) {
        int p = start + t;
        ridx[t] = (p < cnt) ? perm[base + p] : perm[base];  // clamp OOB
    }
    for (int i = t; i < GH_ * E_; i += 256) w2s[i] = Gw2[(size_t)d * GH_ * E_ + i];
    if (t < E_) b2s[t] = Gb2[d * E_ + t];
    __syncthreads();

    const int srow = t >> 2;
    const int sw   = ((t & 3) ^ ((srow >> 1) & 3)) * 8;
    const int myRow = ridx[srow];
    const ushort* aRow = xb + (size_t)myRow * IN_ + sw;
    const ushort* bRow = Gw1t + (size_t)d * GH_ * IN_ + (size_t)srow * IN_ + sw;

    f32x4 acc[4] = {};
    for (int k0 = 0; k0 < IN_; k0 += 32) {
        GLOBAL_LDS16(aRow + k0, As + wave * 512);
        GLOBAL_LDS16(bRow + k0, Bs + wave * 512);
        __syncthreads();

        s16x8 bf = *(const s16x8*)&Bs[(wave * 16 + l16) * 32 + qsw];
        #pragma unroll
        for (int i = 0; i < 4; ++i) {
            s16x8 af = *(const s16x8*)&As[(16 * i + l16) * 32 + qsw];
            acc[i] = __builtin_amdgcn_mfma_f32_16x16x32_bf16(af, bf, acc[i], 0, 0, 0);
        }
        __syncthreads();
    }

    const int hcol = wave * 16 + l16;
    float hb = Gb1[d * GH_ + hcol];
    #pragma unroll
    for (int i = 0; i < 4; ++i)
        #pragma unroll
        for (int r = 0; r < 4; ++r)
            gh[16 * i + quad * 4 + r][hcol] = fmaxf(acc[i][r] + hb, 0.f);
    __syncthreads();

    // layer 2: 64 rows x 6 experts = 384 pairs, strided over 256 threads
    for (int p = t; p < 64 * E_; p += 256) {
        int row = p / E_, e = p - row * E_;
        float s = b2s[e];
        #pragma unroll 8
        for (int h = 0; h < GH_; ++h) s += gh[row][h] * w2s[h * E_ + e];
        lg[row][e] = s;
    }
    __syncthreads();

    if (t < 64 && start + t < cnt) {
        int b = ridx[t];
        float mx = lg[t][0];
        #pragma unroll
        for (int e = 1; e < E_; ++e) mx = fmaxf(mx, lg[t][e]);
        float ex[E_], sum = 0.f;
        #pragma unroll
        for (int e = 0; e < E_; ++e) { ex[e] = expf(lg[t][e] - mx); sum += ex[e]; }
        float inv = 1.f / sum;
        #pragma unroll
        for (int e = 0; e < E_; ++e) gate[(size_t)b * E_ + e] = ex[e] * inv;
    }
}

// ---------------------------------------------------------------------------
// Final: MMoE combine + avg + tower, one wave per sample
// ---------------------------------------------------------------------------
__global__ __launch_bounds__(256) void k_final(
        const float* __restrict__ eo, const float* __restrict__ gate,
        const int* __restrict__ dom,
        const float* __restrict__ Tw1, const float* __restrict__ Tb1,
        const float* __restrict__ Tw2, const float* __restrict__ Tb2,
        float* __restrict__ out) {
    const int wave = threadIdx.x >> 6;
    const int lane = threadIdx.x & 63;
    const int b = blockIdx.x * 4 + wave;
    const int d = dom[b];

    const float* eob = eo + (size_t)b * (E_ * EO_);
    float g[E_];
    #pragma unroll
    for (int e = 0; e < E_; ++e) g[e] = gate[(size_t)b * E_ + e];

    float mmoe[EO_], avg[EO_];
    #pragma unroll
    for (int o = 0; o < EO_; ++o) {
        float m = 0.f, a = 0.f;
        #pragma unroll
        for (int e = 0; e < E_; ++e) {
            float v = eob[e * EO_ + o];
            m += g[e] * v;
            a += v;
        }
        mmoe[o] = m;
        avg[o] = a * (1.0f / E_);
    }

    float acc = Tb1[d * TH_ + lane];
    #pragma unroll
    for (int o = 0; o < EO_; ++o)
        acc += mmoe[o] * Tw1[(size_t)d * EO_ * TH_ + o * TH_ + lane];
    acc = fmaxf(acc, 0.f);

    float s = acc * Tw2[d * TH_ + lane];
    #pragma unroll
    for (int off = 32; off >= 1; off >>= 1) s += __shfl_xor(s, off, 64);

    if (lane == 0)
        out[b] = 1.f / (1.f + expf(-(s + Tb2[d])));
    if (lane < EO_) {
        out[B_ + (size_t)b * EO_ + lane] = avg[lane];
        out[B_ + (size_t)B_ * EO_ + (size_t)b * EO_ + lane] = mmoe[lane];
    }
}

// ---------------------------------------------------------------------------
extern "C" void kernel_launch(void* const* d_in, const int* in_sizes, int n_in,
                              void* d_out, int out_size, void* d_ws, size_t ws_size,
                              hipStream_t stream) {
    const float* x   = (const float*)d_in[0];
    const int*   dom = (const int*)d_in[1];
    const float* Ew1 = (const float*)d_in[2];
    const float* Eb1 = (const float*)d_in[3];
    const float* Ew2 = (const float*)d_in[4];
    const float* Eb2 = (const float*)d_in[5];
    const float* Ew3 = (const float*)d_in[6];
    const float* Eb3 = (const float*)d_in[7];
    const float* Gw1 = (const float*)d_in[8];
    const float* Gb1 = (const float*)d_in[9];
    const float* Gw2 = (const float*)d_in[10];
    const float* Gb2 = (const float*)d_in[11];
    const float* Tw1 = (const float*)d_in[12];
    const float* Tb1 = (const float*)d_in[13];
    const float* Tw2 = (const float*)d_in[14];
    const float* Tb2 = (const float*)d_in[15];
    float* out = (float*)d_out;

    char* ws = (char*)d_ws;
    size_t off = 0;
    auto take = [&](size_t bytes) -> char* {
        char* p = ws + off;
        off = (off + bytes + 255) & ~(size_t)255;
        return p;
    };
    int*    hist    = (int*)take(D_ * 4);
    int*    baseA   = (int*)take(D_ * 4);
    int*    cursor  = (int*)take(D_ * 4);
    int*    perm    = (int*)take(B_ * 4);
    float*  gateBuf = (float*)take((size_t)B_ * E_ * 4);
    float*  eoBuf   = (float*)take((size_t)B_ * E_ * EO_ * 4);
    ushort* xb      = (ushort*)take((size_t)B_ * IN_ * 2);
    ushort* W1t     = (ushort*)take((size_t)E_ * IN_ * EH1_ * 2);
    ushort* W2t     = (ushort*)take((size_t)E_ * EH1_ * EH2_ * 2);
    ushort* G1t     = (ushort*)take((size_t)D_ * IN_ * GH_ * 2);
    size_t fixed = off;

    int G = 1;
    const int cands[4] = {6, 3, 2, 1};
    for (int ci = 0; ci < 4; ++ci) {
        size_t need = fixed + (size_t)cands[ci] * B_ * EH1_ * 2 + 1024;
        if (need <= ws_size) { G = cands[ci]; break; }
    }
    ushort* h1 = (ushort*)take((size_t)G * B_ * EH1_ * 2);

    // fused conversions (cvt + all weight transposes)
    k_prep<<<dim3(PREP_BLKS), dim3(256), 0, stream>>>(
        x, xb, Ew1, W1t, Ew2, W2t, Gw1, G1t);

    // domain bucketing (hist+prefix fused, then scatter)
    k_prefix2<<<dim3(1), dim3(256), 0, stream>>>(dom, hist, baseA, cursor);
    k_scatter<<<dim3(B_ / 256), dim3(256), 0, stream>>>(dom, cursor, perm);

    // gates (selected domain only, MFMA + fused softmax)
    k_gate2<<<dim3((B_ + 63) / 64, D_), dim3(256), 0, stream>>>(
        xb, G1t, Gb1, Gw2, Gb2, perm, baseA, hist, gateBuf);

    // experts: L1 MFMA gemm (repacked epilogue), then fused L2+L3
    for (int g0 = 0; g0 < E_; g0 += G) {
        k_mfma_gemm<<<dim3(EH1_ / 128, B_ / 128, G), dim3(256), 0, stream>>>(
            xb, (size_t)0, W1t, Eb1, h1, B_, EH1_, IN_, g0);
        k_l2eo<<<dim3(B_ / 128, G), dim3(256), 0, stream>>>(
            h1, W2t, Eb2, Ew3, Eb3, eoBuf, g0);
    }

    // combine + towers + outputs
    k_final<<<dim3(B_ / 4), dim3(256), 0, stream>>>(
        eoBuf, gateBuf, dom, Tw1, Tb1, Tw2, Tb2, out);
}

// Round 8
// 321.008 us; speedup vs baseline: 1.2849x; 1.0277x over previous
//
#include <hip/hip_runtime.h>
#include <hip/hip_bf16.h>
#include <math.h>

// Problem constants (HC2MMoE)
#define B_    16384
#define IN_   1024
#define E_    6
#define D_    20
#define EH1_  256
#define EH2_  128
#define EO_   10
#define GH_   64
#define TH_   64

typedef short  s16x8  __attribute__((ext_vector_type(8)));   // 8 bf16 = 4 VGPRs
typedef float  f32x4  __attribute__((ext_vector_type(4)));
typedef float  f32x16 __attribute__((ext_vector_type(16)));

__device__ inline ushort f2bf(float f) {   // RNE fp32 -> bf16 bits
    union { float f; uint32_t u; } v; v.f = f;
    return (ushort)((v.u + 0x7fffu + ((v.u >> 16) & 1u)) >> 16);
}

#define GLOBAL_LDS16(g, l)                                                     \
    __builtin_amdgcn_global_load_lds(                                          \
        (const __attribute__((address_space(1))) void*)(g),                    \
        (__attribute__((address_space(3))) void*)(l), 16, 0, 0)

// ---------------------------------------------------------------------------
// Prep: fused x-convert + 3 weight transposes (flat grid, uniform branch)
// ---------------------------------------------------------------------------
#define CVT_BLKS  (B_ * IN_ / 4 / 256)                       // 16384
#define WT1_TILES ((EH1_ / 32) * (IN_ / 32) * E_)            // 1536
#define WT2_TILES ((EH2_ / 32) * (EH1_ / 32) * E_)           // 192
#define WTG_TILES ((GH_ / 32) * (IN_ / 32) * D_)             // 1280
#define PREP_BLKS (CVT_BLKS + WT1_TILES + WT2_TILES + WTG_TILES)

__global__ __launch_bounds__(256) void k_prep(
        const float* __restrict__ x, ushort* __restrict__ xb,
        const float* __restrict__ Ew1, ushort* __restrict__ W1t,
        const float* __restrict__ Ew2, ushort* __restrict__ W2t,
        const float* __restrict__ Gw1, ushort* __restrict__ G1t) {
    __shared__ float tile[32][33];
    int bid = blockIdx.x;
    const int t = threadIdx.x;

    if (bid < CVT_BLKS) {
        int i = bid * 256 + t;
        float4 v = ((const float4*)x)[i];
        ushort4 o;
        o.x = f2bf(v.x); o.y = f2bf(v.y); o.z = f2bf(v.z); o.w = f2bf(v.w);
        ((ushort4*)xb)[i] = o;
        return;
    }
    bid -= CVT_BLKS;

    const float* W; ushort* Wt; int K, N, z, ky, nx;
    if (bid < WT1_TILES) {
        W = Ew1; Wt = W1t; K = IN_; N = EH1_;
        z = bid / (8 * 32); int r = bid % (8 * 32); ky = r / 8; nx = r % 8;
    } else if (bid < WT1_TILES + WT2_TILES) {
        bid -= WT1_TILES;
        W = Ew2; Wt = W2t; K = EH1_; N = EH2_;
        z = bid / (4 * 8); int r = bid % (4 * 8); ky = r / 4; nx = r % 4;
    } else {
        bid -= WT1_TILES + WT2_TILES;
        W = Gw1; Wt = G1t; K = IN_; N = GH_;
        z = bid / (2 * 32); int r = bid % (2 * 32); ky = r / 2; nx = r % 2;
    }
    const int n0 = nx * 32, k0 = ky * 32;
    const float* We = W + (size_t)z * K * N;
    ushort* Wte = Wt + (size_t)z * K * N;
    const int lx = t & 31, ly = t >> 5;
    #pragma unroll
    for (int r = 0; r < 4; ++r)
        tile[ly + r * 8][lx] = We[(size_t)(k0 + ly + r * 8) * N + n0 + lx];
    __syncthreads();
    #pragma unroll
    for (int r = 0; r < 4; ++r)
        Wte[(size_t)(n0 + ly + r * 8) * K + k0 + lx] = f2bf(tile[lx][ly + r * 8]);
}

// ---------------------------------------------------------------------------
// Fused histogram + prefix (single block, LDS atomics)
// ---------------------------------------------------------------------------
__global__ __launch_bounds__(256) void k_prefix2(
        const int* __restrict__ dom, int* __restrict__ hist,
        int* __restrict__ baseA, int* __restrict__ cursor) {
    __shared__ int h[D_];
    const int t = threadIdx.x;
    if (t < D_) h[t] = 0;
    __syncthreads();
    for (int i = t; i < B_; i += 256) atomicAdd(&h[dom[i]], 1);
    __syncthreads();
    if (t == 0) {
        int s = 0;
        for (int i = 0; i < D_; ++i) {
            baseA[i] = s; cursor[i] = s; hist[i] = h[i]; s += h[i];
        }
    }
}

__global__ void k_scatter(const int* __restrict__ dom, int* __restrict__ cursor,
                          int* __restrict__ perm) {
    int g = blockIdx.x * blockDim.x + threadIdx.x;
    if (g < B_) {
        int pos = atomicAdd(&cursor[dom[g]], 1);
        perm[pos] = g;
    }
}

// ---------------------------------------------------------------------------
// XOR bank-swizzle (verified R5: conflicts -> 0): within each 32-elem k-window
// staged via global_load_lds, physical 16B granule (row, c) holds global chunk
// c ^ ((row>>1)&3).
// ---------------------------------------------------------------------------
#define GBK 32
#define H2P 136

// ---------------------------------------------------------------------------
// bf16 MFMA GEMM, 32x32x16 inner shape: C = relu(A . W + bias), bf16 out.
// 128x128 tile, BK=32, 4 waves each a 64x64 quadrant as 2x2 of 32x32 MFMAs.
// A-frag: m=lane&31, k=(lane>>5)*8+j.  C/D: col=lane&31,
// row=(reg&3)+8*(reg>>2)+4*(lane>>5)  [HW-verified m74/m101].
// ---------------------------------------------------------------------------
__global__ __launch_bounds__(256) void k_mfma_gemm(
        const ushort* __restrict__ A, size_t aStride,
        const ushort* __restrict__ Wt, const float* __restrict__ Bias,
        ushort* __restrict__ C, int M, int N, int K, int eBase) {
    __shared__ __attribute__((aligned(16))) ushort As[128 * GBK];
    __shared__ __attribute__((aligned(16))) ushort Bs[128 * GBK];

    const int z = blockIdx.z;
    const int eAbs = eBase + z;
    const ushort* Ae = A + (size_t)z * aStride;
    const ushort* We = Wt + (size_t)eAbs * (size_t)N * K;
    const float* BiasE = Bias + (size_t)eAbs * N;
    ushort* Ce = C + (size_t)z * (size_t)M * N;

    const int m0 = blockIdx.y * 128;
    const int n0 = blockIdx.x * 128;
    const int t = threadIdx.x;
    const int wave = t >> 6;
    const int lane = t & 63;

    // staging (identical to R5): chunk q = wave*2+{0,1}, swizzled k-offset
    const int q0 = wave * 2, q1 = q0 + 1;
    const int sr0 = q0 * 16 + (lane >> 2);
    const int sr1 = sr0 + 16;                       // (sr1>>1)&3 == (sr0>>1)&3
    const int sw  = ((lane & 3) ^ ((sr0 >> 1) & 3)) * 8;

    const int l32  = lane & 31;
    const int ksel = lane >> 5;                     // k-half selector
    const int rw = (wave & 1) * 64;
    const int cw = (wave >> 1) * 64;

    // per-fragment row indices + their swizzle keys (loop-invariant)
    int rowA[2], rowB[2], swzA[2], swzB[2];
    #pragma unroll
    for (int i = 0; i < 2; ++i) {
        rowA[i] = rw + 32 * i + l32;  swzA[i] = (rowA[i] >> 1) & 3;
        rowB[i] = cw + 32 * i + l32;  swzB[i] = (rowB[i] >> 1) & 3;
    }

    f32x16 acc[2][2] = {};

    for (int k0 = 0; k0 < K; k0 += GBK) {
        GLOBAL_LDS16(Ae + (size_t)(m0 + sr0) * K + k0 + sw, As + q0 * 512);
        GLOBAL_LDS16(Ae + (size_t)(m0 + sr1) * K + k0 + sw, As + q1 * 512);
        GLOBAL_LDS16(We + (size_t)(n0 + sr0) * K + k0 + sw, Bs + q0 * 512);
        GLOBAL_LDS16(We + (size_t)(n0 + sr1) * K + k0 + sw, Bs + q1 * 512);
        __syncthreads();

        #pragma unroll
        for (int h = 0; h < 2; ++h) {           // two K=16 halves per window
            const int cb = h * 2 + ksel;        // logical 8-elem chunk
            s16x8 af[2], bf[2];
            #pragma unroll
            for (int i = 0; i < 2; ++i)
                af[i] = *(const s16x8*)&As[rowA[i] * GBK + ((cb ^ swzA[i]) * 8)];
            #pragma unroll
            for (int j = 0; j < 2; ++j)
                bf[j] = *(const s16x8*)&Bs[rowB[j] * GBK + ((cb ^ swzB[j]) * 8)];
            #pragma unroll
            for (int i = 0; i < 2; ++i)
                #pragma unroll
                for (int j = 0; j < 2; ++j)
                    acc[i][j] = __builtin_amdgcn_mfma_f32_32x32x16_bf16(
                        af[i], bf[j], acc[i][j], 0, 0, 0);
        }
        __syncthreads();
    }

    // epilogue: direct stores (R5 style), 32x32 C/D layout
    float bi[2];
    #pragma unroll
    for (int j = 0; j < 2; ++j) bi[j] = BiasE[n0 + cw + 32 * j + l32];

    #pragma unroll
    for (int i = 0; i < 2; ++i) {
        #pragma unroll
        for (int reg = 0; reg < 16; ++reg) {
            int rowin = (reg & 3) + 8 * (reg >> 2) + 4 * ksel;
            ushort* crow = Ce + (size_t)(m0 + rw + 32 * i + rowin) * N;
            #pragma unroll
            for (int j = 0; j < 2; ++j) {
                float v = fmaxf(acc[i][j][reg] + bi[j], 0.f);
                crow[n0 + cw + 32 * j + l32] = f2bf(v);
            }
        }
    }
}

// ---------------------------------------------------------------------------
// Fused expert L2+L3 (unchanged, 16x16x32): h2 = relu(h1 . W2^T + Eb2), then
// eo = h2 . Ew3 + Eb3 in-block.
// ---------------------------------------------------------------------------
__global__ __launch_bounds__(256) void k_l2eo(
        const ushort* __restrict__ h1, const ushort* __restrict__ W2t,
        const float* __restrict__ Eb2, const float* __restrict__ Ew3,
        const float* __restrict__ Eb3, float* __restrict__ eo, int eBase) {
    __shared__ __attribute__((aligned(16))) ushort smem[17408 + 16 * H2P];
    ushort* As = smem;            // 128*32 elems (main loop)
    ushort* Bs = smem + 4096;     // 128*32 elems (main loop)

    const int z = blockIdx.y;
    const int eAbs = eBase + z;
    const ushort* Ae = h1 + (size_t)z * B_ * EH1_;
    const ushort* We = W2t + (size_t)eAbs * EH2_ * EH1_;   // [N=128][K=256]

    const int m0 = blockIdx.x * 128;
    const int t = threadIdx.x;
    const int wave = t >> 6;
    const int lane = t & 63;

    const int q0 = wave * 2, q1 = q0 + 1;
    const int sr0 = q0 * 16 + (lane >> 2);
    const int sr1 = sr0 + 16;
    const int sw  = ((lane & 3) ^ ((sr0 >> 1) & 3)) * 8;

    const int quad = lane >> 4;
    const int l16  = lane & 15;
    const int qsw  = (quad ^ ((l16 >> 1) & 3)) * 8;
    const int rw = (wave & 1) * 64;
    const int cw = (wave >> 1) * 64;

    f32x4 acc[4][4] = {};

    for (int k0 = 0; k0 < EH1_; k0 += GBK) {
        GLOBAL_LDS16(Ae + (size_t)(m0 + sr0) * EH1_ + k0 + sw, As + q0 * 512);
        GLOBAL_LDS16(Ae + (size_t)(m0 + sr1) * EH1_ + k0 + sw, As + q1 * 512);
        GLOBAL_LDS16(We + (size_t)sr0 * EH1_ + k0 + sw, Bs + q0 * 512);
        GLOBAL_LDS16(We + (size_t)sr1 * EH1_ + k0 + sw, Bs + q1 * 512);
        __syncthreads();

        s16x8 af[4], bf[4];
        #pragma unroll
        for (int i = 0; i < 4; ++i)
            af[i] = *(const s16x8*)&As[(rw + 16 * i + l16) * GBK + qsw];
        #pragma unroll
        for (int j = 0; j < 4; ++j)
            bf[j] = *(const s16x8*)&Bs[(cw + 16 * j + l16) * GBK + qsw];
        #pragma unroll
        for (int i = 0; i < 4; ++i)
            #pragma unroll
            for (int j = 0; j < 4; ++j)
                acc[i][j] = __builtin_amdgcn_mfma_f32_16x16x32_bf16(
                    af[i], bf[j], acc[i][j], 0, 0, 0);
        __syncthreads();
    }

    // epilogue: h2 tile (bias+relu, bf16) -> LDS in A-readable layout
    ushort* h2L = smem;             // [128][H2P]
    ushort* E3t = smem + 128 * H2P; // [16][H2P]  (cols >= EO_ zero)

    float bi[4];
    #pragma unroll
    for (int j = 0; j < 4; ++j) bi[j] = Eb2[eAbs * EH2_ + cw + 16 * j + l16];

    #pragma unroll
    for (int i = 0; i < 4; ++i)
        #pragma unroll
        for (int r = 0; r < 4; ++r) {
            int row = rw + 16 * i + quad * 4 + r;
            #pragma unroll
            for (int j = 0; j < 4; ++j)
                h2L[row * H2P + cw + 16 * j + l16] =
                    f2bf(fmaxf(acc[i][j][r] + bi[j], 0.f));
        }

    for (int i = t; i < 16 * 128; i += 256) {
        int col = i >> 7, k = i & 127;
        float v = (col < EO_) ? Ew3[(size_t)eAbs * EH2_ * EO_ + k * EO_ + col] : 0.f;
        E3t[col * H2P + k] = f2bf(v);
    }
    __syncthreads();

    #pragma unroll
    for (int gi = 0; gi < 2; ++gi) {
        int g = wave * 2 + gi;
        f32x4 acc2 = {};
        #pragma unroll
        for (int kc = 0; kc < 4; ++kc) {
            s16x8 a = *(const s16x8*)&h2L[(g * 16 + l16) * H2P + kc * 32 + quad * 8];
            s16x8 b = *(const s16x8*)&E3t[l16 * H2P + kc * 32 + quad * 8];
            acc2 = __builtin_amdgcn_mfma_f32_16x16x32_bf16(a, b, acc2, 0, 0, 0);
        }
        if (l16 < EO_) {
            float b3 = Eb3[eAbs * EO_ + l16];
            #pragma unroll
            for (int r = 0; r < 4; ++r) {
                int row = m0 + g * 16 + quad * 4 + r;
                eo[(size_t)row * (E_ * EO_) + eAbs * EO_ + l16] = acc2[r] + b3;
            }
        }
    }
}

// ---------------------------------------------------------------------------
// Gate (MFMA, fused): per (domain, 64-row tile) block, with bank swizzle.
// ---------------------------------------------------------------------------
__global__ __launch_bounds__(256) void k_gate2(
        const ushort* __restrict__ xb, const ushort* __restrict__ Gw1t,
        const float* __restrict__ Gb1, const float* __restrict__ Gw2,
        const float* __restrict__ Gb2, const int* __restrict__ perm,
        const int* __restrict__ baseA, const int* __restrict__ cntA,
        float* __restrict__ gate) {
    const int d = blockIdx.y;
    const int cnt = cntA[d];
    const int start = blockIdx.x * 64;
    if (start >= cnt) return;
    const int base = baseA[d];

    __shared__ __attribute__((aligned(16))) ushort As[64 * 32];
    __shared__ __attribute__((aligned(16))) ushort Bs[64 * 32];
    __shared__ int    ridx[64];
    __shared__ float  gh[64][GH_ + 1];
    __shared__ float  w2s[GH_ * E_];
    __shared__ float  b2s[E_];
    __shared__ float  lg[64][E_];

    const int t = threadIdx.x;
    const int wave = t >> 6;
    const int lane = t & 63;
    const int quad = lane >> 4;
    const int l16  = lane & 15;
    const int qsw  = (quad ^ ((l16 >> 1) & 3)) * 8;

    if (t < 64) {
        int p = start + t;
        ridx[t] = (p < cnt) ? perm[base + p] : perm[base];  // clamp OOB
    }
    for (int i = t; i < GH_ * E_; i += 256) w2s[i] = Gw2[(size_t)d * GH_ * E_ + i];
    if (t < E_) b2s[t] = Gb2[d * E_ + t];
    __syncthreads();

    const int srow = t >> 2;
    const int sw   = ((t & 3) ^ ((srow >> 1) & 3)) * 8;
    const int myRow = ridx[srow];
    const ushort* aRow = xb + (size_t)myRow * IN_ + sw;
    const ushort* bRow = Gw1t + (size_t)d * GH_ * IN_ + (size_t)srow * IN_ + sw;

    f32x4 acc[4] = {};
    for (int k0 = 0; k0 < IN_; k0 += 32) {
        GLOBAL_LDS16(aRow + k0, As + wave * 512);
        GLOBAL_LDS16(bRow + k0, Bs + wave * 512);
        __syncthreads();

        s16x8 bf = *(const s16x8*)&Bs[(wave * 16 + l16) * 32 + qsw];
        #pragma unroll
        for (int i = 0; i < 4; ++i) {
            s16x8 af = *(const s16x8*)&As[(16 * i + l16) * 32 + qsw];
            acc[i] = __builtin_amdgcn_mfma_f32_16x16x32_bf16(af, bf, acc[i], 0, 0, 0);
        }
        __syncthreads();
    }

    const int hcol = wave * 16 + l16;
    float hb = Gb1[d * GH_ + hcol];
    #pragma unroll
    for (int i = 0; i < 4; ++i)
        #pragma unroll
        for (int r = 0; r < 4; ++r)
            gh[16 * i + quad * 4 + r][hcol] = fmaxf(acc[i][r] + hb, 0.f);
    __syncthreads();

    // layer 2: 64 rows x 6 experts = 384 pairs, strided over 256 threads
    for (int p = t; p < 64 * E_; p += 256) {
        int row = p / E_, e = p - row * E_;
        float s = b2s[e];
        #pragma unroll 8
        for (int h = 0; h < GH_; ++h) s += gh[row][h] * w2s[h * E_ + e];
        lg[row][e] = s;
    }
    __syncthreads();

    if (t < 64 && start + t < cnt) {
        int b = ridx[t];
        float mx = lg[t][0];
        #pragma unroll
        for (int e = 1; e < E_; ++e) mx = fmaxf(mx, lg[t][e]);
        float ex[E_], sum = 0.f;
        #pragma unroll
        for (int e = 0; e < E_; ++e) { ex[e] = expf(lg[t][e] - mx); sum += ex[e]; }
        float inv = 1.f / sum;
        #pragma unroll
        for (int e = 0; e < E_; ++e) gate[(size_t)b * E_ + e] = ex[e] * inv;
    }
}

// ---------------------------------------------------------------------------
// Final: MMoE combine + avg + tower, one wave per sample
// ---------------------------------------------------------------------------
__global__ __launch_bounds__(256) void k_final(
        const float* __restrict__ eo, const float* __restrict__ gate,
        const int* __restrict__ dom,
        const float* __restrict__ Tw1, const float* __restrict__ Tb1,
        const float* __restrict__ Tw2, const float* __restrict__ Tb2,
        float* __restrict__ out) {
    const int wave = threadIdx.x >> 6;
    const int lane = threadIdx.x & 63;
    const int b = blockIdx.x * 4 + wave;
    const int d = dom[b];

    const float* eob = eo + (size_t)b * (E_ * EO_);
    float g[E_];
    #pragma unroll
    for (int e = 0; e < E_; ++e) g[e] = gate[(size_t)b * E_ + e];

    float mmoe[EO_], avg[EO_];
    #pragma unroll
    for (int o = 0; o < EO_; ++o) {
        float m = 0.f, a = 0.f;
        #pragma unroll
        for (int e = 0; e < E_; ++e) {
            float v = eob[e * EO_ + o];
            m += g[e] * v;
            a += v;
        }
        mmoe[o] = m;
        avg[o] = a * (1.0f / E_);
    }

    float acc = Tb1[d * TH_ + lane];
    #pragma unroll
    for (int o = 0; o < EO_; ++o)
        acc += mmoe[o] * Tw1[(size_t)d * EO_ * TH_ + o * TH_ + lane];
    acc = fmaxf(acc, 0.f);

    float s = acc * Tw2[d * TH_ + lane];
    #pragma unroll
    for (int off = 32; off >= 1; off >>= 1) s += __shfl_xor(s, off, 64);

    if (lane == 0)
        out[b] = 1.f / (1.f + expf(-(s + Tb2[d])));
    if (lane < EO_) {
        out[B_ + (size_t)b * EO_ + lane] = avg[lane];
        out[B_ + (size_t)B_ * EO_ + (size_t)b * EO_ + lane] = mmoe[lane];
    }
}

// ---------------------------------------------------------------------------
extern "C" void kernel_launch(void* const* d_in, const int* in_sizes, int n_in,
                              void* d_out, int out_size, void* d_ws, size_t ws_size,
                              hipStream_t stream) {
    const float* x   = (const float*)d_in[0];
    const int*   dom = (const int*)d_in[1];
    const float* Ew1 = (const float*)d_in[2];
    const float* Eb1 = (const float*)d_in[3];
    const float* Ew2 = (const float*)d_in[4];
    const float* Eb2 = (const float*)d_in[5];
    const float* Ew3 = (const float*)d_in[6];
    const float* Eb3 = (const float*)d_in[7];
    const float* Gw1 = (const float*)d_in[8];
    const float* Gb1 = (const float*)d_in[9];
    const float* Gw2 = (const float*)d_in[10];
    const float* Gb2 = (const float*)d_in[11];
    const float* Tw1 = (const float*)d_in[12];
    const float* Tb1 = (const float*)d_in[13];
    const float* Tw2 = (const float*)d_in[14];
    const float* Tb2 = (const float*)d_in[15];
    float* out = (float*)d_out;

    char* ws = (char*)d_ws;
    size_t off = 0;
    auto take = [&](size_t bytes) -> char* {
        char* p = ws + off;
        off = (off + bytes + 255) & ~(size_t)255;
        return p;
    };
    int*    hist    = (int*)take(D_ * 4);
    int*    baseA   = (int*)take(D_ * 4);
    int*    cursor  = (int*)take(D_ * 4);
    int*    perm    = (int*)take(B_ * 4);
    float*  gateBuf = (float*)take((size_t)B_ * E_ * 4);
    float*  eoBuf   = (float*)take((size_t)B_ * E_ * EO_ * 4);
    ushort* xb      = (ushort*)take((size_t)B_ * IN_ * 2);
    ushort* W1t     = (ushort*)take((size_t)E_ * IN_ * EH1_ * 2);
    ushort* W2t     = (ushort*)take((size_t)E_ * EH1_ * EH2_ * 2);
    ushort* G1t     = (ushort*)take((size_t)D_ * IN_ * GH_ * 2);
    size_t fixed = off;

    int G = 1;
    const int cands[4] = {6, 3, 2, 1};
    for (int ci = 0; ci < 4; ++ci) {
        size_t need = fixed + (size_t)cands[ci] * B_ * EH1_ * 2 + 1024;
        if (need <= ws_size) { G = cands[ci]; break; }
    }
    ushort* h1 = (ushort*)take((size_t)G * B_ * EH1_ * 2);

    // fused conversions (cvt + all weight transposes)
    k_prep<<<dim3(PREP_BLKS), dim3(256), 0, stream>>>(
        x, xb, Ew1, W1t, Ew2, W2t, Gw1, G1t);

    // domain bucketing (hist+prefix fused, then scatter)
    k_prefix2<<<dim3(1), dim3(256), 0, stream>>>(dom, hist, baseA, cursor);
    k_scatter<<<dim3(B_ / 256), dim3(256), 0, stream>>>(dom, cursor, perm);

    // gates (selected domain only, MFMA + fused softmax)
    k_gate2<<<dim3((B_ + 63) / 64, D_), dim3(256), 0, stream>>>(
        xb, G1t, Gb1, Gw2, Gb2, perm, baseA, hist, gateBuf);

    // experts: L1 MFMA gemm (32x32x16), then fused L2+L3
    for (int g0 = 0; g0 < E_; g0 += G) {
        k_mfma_gemm<<<dim3(EH1_ / 128, B_ / 128, G), dim3(256), 0, stream>>>(
            xb, (size_t)0, W1t, Eb1, h1, B_, EH1_, IN_, g0);
        k_l2eo<<<dim3(B_ / 128, G), dim3(256), 0, stream>>>(
            h1, W2t, Eb2, Ew3, Eb3, eoBuf, g0);
    }

    // combine + towers + outputs
    k_final<<<dim3(B_ / 4), dim3(256), 0, stream>>>(
        eoBuf, gateBuf, dom, Tw1, Tb1, Tw2, Tb2, out);
}